// Round 1
// 5535.534 us; speedup vs baseline: 2.7759x; 2.7759x over previous
//
#include <hip/hip_runtime.h>

// All tensors fp32 (reference uses jnp.float32 throughout); captions int32.
//
// Round theory: the old scan_f32 ran 16 WGs on 256 CUs (Occupancy 0.74%,
// VALUBusy 1.5%) -> latency/parallelism bound, 13.9 ms of 15.4 ms total.
// This round: (1) hoist the h-independent half of the GRU input GEMM
// (embedding part) out of the scan as a precomputed GEMM Gemb[3200,1536];
// (2) run the recurrence as 50 per-step kernel launches (kernel boundary =
// the only needed grid sync, since h is the only cross-WG dependency);
// (3) per-step grid = 64 WGs (16 batch-groups x 4 gate-slices) x 512 thr,
// 4 batches share every weight load, all 3 gates of a j-slice live in one
// WG so the GRU combine is LDS-local.

static __device__ __forceinline__ float my_tanh(float x) {
    x = fminf(fmaxf(x, -15.f), 15.f);
    float e = __expf(2.f * x);
    return (e - 1.f) / (e + 1.f);
}
static __device__ __forceinline__ float my_sigmoid(float x) {
    return 1.f / (1.f + __expf(-x));
}

// ---------------------------------------------------------------------------
// Tiled fp32 transpose: out[c*R + r] = in[r*ld_in + c]
// ---------------------------------------------------------------------------
__global__ __launch_bounds__(256) void transpose_f32(
    const float* __restrict__ in, float* __restrict__ out,
    int R, int C, int ld_in)
{
    __shared__ float tile[32][33];
    int tc = blockIdx.x * 32;
    int tr = blockIdx.y * 32;
    int tx = threadIdx.x & 31, ty = threadIdx.x >> 5;  // 32 x 8
    #pragma unroll
    for (int i = 0; i < 4; i++) {
        int r = tr + ty + i * 8, c = tc + tx;
        tile[ty + i * 8][tx] = (r < R && c < C) ? in[(long)r * ld_in + c] : 0.f;
    }
    __syncthreads();
    #pragma unroll
    for (int i = 0; i < 4; i++) {
        int c = tc + ty + i * 8, r = tr + tx;
        if (c < C && r < R) out[(long)c * R + r] = tile[tx][ty + i * 8];
    }
}

// ---------------------------------------------------------------------------
// Simple fp32 GEMM: C[m0..m0+16, n] = A[M,K] @ B[K,N] + bias.
// Thread per output column, 16 rows per block, A-tile staged in LDS (32 KB).
// Requires M%16==0, K%512==0; N-edge masked.
// ---------------------------------------------------------------------------
__global__ __launch_bounds__(256) void gemm_f32(
    const float* __restrict__ A, int lda,
    const float* __restrict__ B, int ldb,
    const float* __restrict__ bias,
    float* __restrict__ C, int ldc,
    int M, int N, int K)
{
    __shared__ float Asm[16 * 512];
    const int tid = threadIdx.x;
    const int n = blockIdx.x * 256 + tid;
    const bool active = n < N;
    const int nn = active ? n : (N - 1);
    const int m0 = blockIdx.y * 16;

    float acc[16];
    #pragma unroll
    for (int i = 0; i < 16; i++) acc[i] = 0.f;

    for (int kt = 0; kt < K; kt += 512) {
        for (int idx = tid; idx < 16 * 512; idx += 256) {
            int i = idx >> 9, kk = idx & 511;
            Asm[idx] = A[(long)(m0 + i) * lda + kt + kk];
        }
        __syncthreads();
        for (int k0 = 0; k0 < 512; k0 += 4) {
            float4 a4[16];
            #pragma unroll
            for (int i = 0; i < 16; i++)
                a4[i] = *(const float4*)(&Asm[i * 512 + k0]);
            #pragma unroll
            for (int j = 0; j < 4; j++) {
                float bv = B[(long)(kt + k0 + j) * ldb + nn];
                #pragma unroll
                for (int i = 0; i < 16; i++) {
                    float av = (j == 0) ? a4[i].x : (j == 1) ? a4[i].y
                             : (j == 2) ? a4[i].z : a4[i].w;
                    acc[i] = fmaf(av, bv, acc[i]);
                }
            }
        }
        __syncthreads();
    }

    if (active) {
        float bb = bias ? bias[n] : 0.f;
        #pragma unroll
        for (int i = 0; i < 16; i++)
            C[(long)(m0 + i) * ldc + n] = acc[i] + bb;
    }
}

// ---------------------------------------------------------------------------
// Gather embedding rows: out[m,:] = emb[caps[m],:]  (m = b*50+t, 3200 rows)
// ---------------------------------------------------------------------------
__global__ __launch_bounds__(256) void gather_emb(
    const int* __restrict__ caps, const float* __restrict__ emb,
    float* __restrict__ out)
{
    const int m = blockIdx.x;
    const int cap = caps[m];
    const float* src = emb + (size_t)cap * 512;
    float* dst = out + (size_t)m * 512;
    dst[threadIdx.x] = src[threadIdx.x];
    dst[threadIdx.x + 256] = src[threadIdx.x + 256];
}

// ---------------------------------------------------------------------------
// One time step of the decoder. Grid: 64 WGs = 16 batch-groups x 4 j-slices;
// 512 threads. Each WG handles 4 batch elements and hidden units
// j in [q*128, q*128+128) -> gate columns n = g*512 + q*128 + jj, g=0..2.
// Threads 0..383: one gate column each (4 batch accumulators, shared weight
// load). Threads 384..511: att2 (two j's each, float2 W_da loads).
// Attention is recomputed per q-slice (x4 redundancy) to keep the step free
// of cross-WG dependencies; only h crosses the kernel boundary.
// LDS: 36.9 KB.
// ---------------------------------------------------------------------------
__global__ __launch_bounds__(512) void scan_step(
    const int t,
    const float* __restrict__ enc,      // [64,49,512]
    const float* __restrict__ att1,     // [64,49,256]
    const float* __restrict__ W_da,     // [512,256]  k-major
    const float* __restrict__ b_da,     // [256]
    const float* __restrict__ W_fa,     // [256]
    const float* __restrict__ b_fa,     // [1]
    const float* __restrict__ Wt_ih,    // [1024,1536] (rows 512.. = ctx part)
    const float* __restrict__ Wt_hh,    // [512,1536]
    const float* __restrict__ b_hh,     // [1536]
    const float* __restrict__ Gemb,     // [3200,1536] = emb_t@W_ih(emb) + b_ih
    float* __restrict__ h_g,            // [64,512]
    float* __restrict__ Hbuf)           // [3200,512]
{
    __shared__ float sh_h[2048];        // h, 4 batches
    __shared__ float sh_c[2048];        // context, 4 batches
    __shared__ float sh_gh[4 * 384];    // [bb][g*128+jj]
    __shared__ float sh_gi[4 * 384];
    __shared__ float sh_att2[4 * 256];
    __shared__ float sh_red[4 * 196];   // [bb][jg*49+l]
    __shared__ float sh_s[4 * 64];      // alpha

    const int tid = threadIdx.x;
    const int bg = blockIdx.x >> 2;     // 0..15
    const int q  = blockIdx.x & 3;      // 0..3
    const int b0 = bg * 4;

    // ---- stage h
    if (t == 0) {
        for (int i = tid; i < 2048; i += 512) sh_h[i] = 0.f;
    } else {
        for (int i = tid; i < 2048; i += 512) sh_h[i] = h_g[(size_t)b0 * 512 + i];
    }
    __syncthreads();

    // ---- gh = h @ W_hh^T + b_hh (384 cols) || att2 = h @ W_da + b_da
    if (tid < 384) {
        const int n = (tid >> 7) * 512 + q * 128 + (tid & 127);
        float a0 = 0.f, a1 = 0.f, a2 = 0.f, a3 = 0.f;
        #pragma unroll 8
        for (int k = 0; k < 512; ++k) {
            const float w = Wt_hh[(size_t)k * 1536 + n];
            a0 = fmaf(sh_h[k],        w, a0);
            a1 = fmaf(sh_h[512 + k],  w, a1);
            a2 = fmaf(sh_h[1024 + k], w, a2);
            a3 = fmaf(sh_h[1536 + k], w, a3);
        }
        const float bb = b_hh[n];
        sh_gh[tid]        = a0 + bb;
        sh_gh[384 + tid]  = a1 + bb;
        sh_gh[768 + tid]  = a2 + bb;
        sh_gh[1152 + tid] = a3 + bb;
    } else {
        const int j0 = (tid - 384) * 2;
        float a00=0,a01=0,a10=0,a11=0,a20=0,a21=0,a30=0,a31=0;
        #pragma unroll 8
        for (int k = 0; k < 512; ++k) {
            const float2 w = *(const float2*)(W_da + (size_t)k * 256 + j0);
            const float h0 = sh_h[k],        h1 = sh_h[512 + k];
            const float h2 = sh_h[1024 + k], h3 = sh_h[1536 + k];
            a00 = fmaf(h0, w.x, a00); a01 = fmaf(h0, w.y, a01);
            a10 = fmaf(h1, w.x, a10); a11 = fmaf(h1, w.y, a11);
            a20 = fmaf(h2, w.x, a20); a21 = fmaf(h2, w.y, a21);
            a30 = fmaf(h3, w.x, a30); a31 = fmaf(h3, w.y, a31);
        }
        const float bd0 = b_da[j0], bd1 = b_da[j0 + 1];
        sh_att2[j0]           = a00 + bd0; sh_att2[j0 + 1]       = a01 + bd1;
        sh_att2[256 + j0]     = a10 + bd0; sh_att2[256 + j0 + 1] = a11 + bd1;
        sh_att2[512 + j0]     = a20 + bd0; sh_att2[512 + j0 + 1] = a21 + bd1;
        sh_att2[768 + j0]     = a30 + bd0; sh_att2[768 + j0 + 1] = a31 + bd1;
    }
    __syncthreads();

    // ---- score partials: 4b x 4jg x 49l = 784 tasks (lane-major in l so
    // sh_att2 reads broadcast within a wave)
    for (int task = tid; task < 784; task += 512) {
        const int bb = task / 196;
        const int r  = task - bb * 196;
        const int jg = r / 49;
        const int l  = r - jg * 49;
        const float4* ar4 =
            (const float4*)(att1 + ((size_t)(b0 + bb) * 49 + l) * 256 + jg * 64);
        const float* at2 = sh_att2 + bb * 256 + jg * 64;
        const float* wf  = W_fa + jg * 64;
        float sp = 0.f;
        #pragma unroll
        for (int j4 = 0; j4 < 16; ++j4) {
            const float4 v = ar4[j4];
            sp += my_tanh(v.x + at2[j4 * 4 + 0]) * wf[j4 * 4 + 0];
            sp += my_tanh(v.y + at2[j4 * 4 + 1]) * wf[j4 * 4 + 1];
            sp += my_tanh(v.z + at2[j4 * 4 + 2]) * wf[j4 * 4 + 2];
            sp += my_tanh(v.w + at2[j4 * 4 + 3]) * wf[j4 * 4 + 3];
        }
        sh_red[bb * 196 + jg * 49 + l] = sp;
    }
    __syncthreads();
    if (tid < 196) {
        const int bb = tid / 49, l = tid - bb * 49;
        const float* rd = sh_red + bb * 196;
        sh_s[bb * 64 + l] = rd[l] + rd[49 + l] + rd[98 + l] + rd[147 + l] + b_fa[0];
    }
    __syncthreads();
    // ---- softmax over L=49 (thread per batch)
    if (tid < 4) {
        float* al = sh_s + tid * 64;
        float m = al[0];
        for (int l = 1; l < 49; ++l) m = fmaxf(m, al[l]);
        float su = 0.f;
        for (int l = 0; l < 49; ++l) { const float e = __expf(al[l] - m); al[l] = e; su += e; }
        const float inv = 1.f / su;
        for (int l = 0; l < 49; ++l) al[l] *= inv;
    }
    __syncthreads();
    // ---- context[b][d] = sum_l alpha * enc
    for (int i = tid; i < 2048; i += 512) {
        const int bb = i >> 9, d = i & 511;
        const float* e0 = enc + (size_t)(b0 + bb) * 49 * 512 + d;
        const float* al = sh_s + bb * 64;
        float c = 0.f;
        #pragma unroll
        for (int l = 0; l < 49; ++l) c = fmaf(al[l], e0[(size_t)l * 512], c);
        sh_c[i] = c;
    }
    __syncthreads();

    // ---- gi = Gemb (precomputed emb part + b_ih) + context @ W_ih(ctx)^T
    if (tid < 384) {
        const int n = (tid >> 7) * 512 + q * 128 + (tid & 127);
        const float* Wc = Wt_ih + (size_t)512 * 1536;
        float a0 = 0.f, a1 = 0.f, a2 = 0.f, a3 = 0.f;
        #pragma unroll 8
        for (int k = 0; k < 512; ++k) {
            const float w = Wc[(size_t)k * 1536 + n];
            a0 = fmaf(sh_c[k],        w, a0);
            a1 = fmaf(sh_c[512 + k],  w, a1);
            a2 = fmaf(sh_c[1024 + k], w, a2);
            a3 = fmaf(sh_c[1536 + k], w, a3);
        }
        const size_t gb = ((size_t)b0 * 50 + t) * 1536 + n;
        sh_gi[tid]        = a0 + Gemb[gb];
        sh_gi[384 + tid]  = a1 + Gemb[gb + 76800];    // +1*50*1536
        sh_gi[768 + tid]  = a2 + Gemb[gb + 153600];
        sh_gi[1152 + tid] = a3 + Gemb[gb + 230400];
    }
    __syncthreads();

    // ---- GRU combine: 4b x 128j = 512 tasks, one per thread
    {
        const int bb = tid >> 7, jj = tid & 127;
        const int j = q * 128 + jj;
        const float* gi = sh_gi + bb * 384;
        const float* gh = sh_gh + bb * 384;
        const float r  = my_sigmoid(gi[jj] + gh[jj]);
        const float z  = my_sigmoid(gi[128 + jj] + gh[128 + jj]);
        const float nn = my_tanh(gi[256 + jj] + r * gh[256 + jj]);
        const float hnew = (1.f - z) * nn + z * sh_h[bb * 512 + j];
        h_g[(size_t)(b0 + bb) * 512 + j] = hnew;
        Hbuf[((size_t)(b0 + bb) * 50 + t) * 512 + j] = hnew;
    }
}

// ---------------------------------------------------------------------------
extern "C" void kernel_launch(void* const* d_in, const int* in_sizes, int n_in,
                              void* d_out, int out_size, void* d_ws, size_t ws_size,
                              hipStream_t stream) {
    const float* spatial = (const float*)d_in[0];
    const int*   captions= (const int*)d_in[1];
    const float* W_feat  = (const float*)d_in[2];
    const float* b_feat  = (const float*)d_in[3];
    const float* W_ea    = (const float*)d_in[4];
    const float* b_ea    = (const float*)d_in[5];
    const float* W_da    = (const float*)d_in[6];
    const float* b_da    = (const float*)d_in[7];
    const float* W_fa    = (const float*)d_in[8];
    const float* b_fa    = (const float*)d_in[9];
    const float* emb     = (const float*)d_in[10];
    const float* W_ih    = (const float*)d_in[11];
    const float* W_hh    = (const float*)d_in[12];
    const float* b_ih    = (const float*)d_in[13];
    const float* b_hh    = (const float*)d_in[14];
    const float* W_fc    = (const float*)d_in[15];
    const float* b_fc    = (const float*)d_in[16];
    float* out = (float*)d_out;

    // Workspace: 45.4 MB fp32. Embt aliases Hbuf (Embt consumed by the Gemb
    // GEMM before the scan writes Hbuf; same-stream ordering guarantees it).
    char* ws = (char*)d_ws;
    float* Wt_ih = (float*)ws; ws += (size_t)1024 * 1536 * 4;   //  6,291,456
    float* Wt_hh = (float*)ws; ws += (size_t)512 * 1536 * 4;    //  3,145,728
    float* enc   = (float*)ws; ws += (size_t)3136 * 512 * 4;    //  6,422,528
    float* att1  = (float*)ws; ws += (size_t)3136 * 256 * 4;    //  3,211,264
    float* Hbuf  = (float*)ws; ws += (size_t)3200 * 512 * 4;    //  6,553,600
    float* Gemb  = (float*)ws; ws += (size_t)3200 * 1536 * 4;   // 19,660,800
    float* h_g   = (float*)ws; ws += (size_t)64 * 512 * 4;      //    131,072
    float* Embt  = Hbuf;
    const size_t NEED = 6291456ull + 3145728 + 6422528 + 3211264 + 6553600
                      + 19660800 + 131072;
    if (ws_size < NEED) return;

    dim3 blk(256);
    // Wt_ih[1024,1536] = W_ih[1536,1024]^T ; Wt_hh[512,1536] = W_hh[1536,512]^T
    transpose_f32<<<dim3(32, 48), blk, 0, stream>>>(W_ih, Wt_ih, 1536, 1024, 1024);
    transpose_f32<<<dim3(16, 48), blk, 0, stream>>>(W_hh, Wt_hh, 1536, 512, 512);

    // Embt[m,:] = emb[captions[m],:]          [3200,512]  (m = b*50+t)
    gather_emb<<<dim3(3200), blk, 0, stream>>>(captions, emb, Embt);

    // enc = spatial @ W_feat + b_feat         [3136,512]
    gemm_f32<<<dim3(2, 196), blk, 0, stream>>>(spatial, 2048, W_feat, 512, b_feat,
                                               enc, 512, 3136, 512, 2048);
    // att1 = enc @ W_ea + b_ea                [3136,256]
    gemm_f32<<<dim3(1, 196), blk, 0, stream>>>(enc, 512, W_ea, 256, b_ea,
                                               att1, 256, 3136, 256, 512);
    // Gemb = Embt @ Wt_ih[0:512,:] + b_ih     [3200,1536]  (h-independent gi)
    gemm_f32<<<dim3(6, 200), blk, 0, stream>>>(Embt, 512, Wt_ih, 1536, b_ih,
                                               Gemb, 1536, 3200, 1536, 512);

    // recurrent scan: 50 per-step launches (kernel boundary = grid sync on h)
    for (int t = 0; t < 50; ++t)
        scan_step<<<dim3(64), dim3(512), 0, stream>>>(t, enc, att1,
                                                      W_da, b_da, W_fa, b_fa,
                                                      Wt_ih, Wt_hh, b_hh,
                                                      Gemb, h_g, Hbuf);

    // logits = Hbuf @ W_fc + b_fc -> d_out    [3200,10000]
    gemm_f32<<<dim3(40, 200), blk, 0, stream>>>(Hbuf, 512, W_fc, 10000, b_fc,
                                                out, 10000, 3200, 10000, 512);
}

// Round 2
// 3259.377 us; speedup vs baseline: 4.7144x; 1.6983x over previous
//
#include <hip/hip_runtime.h>

// fp32 everywhere (reference is jnp.float32); captions int32.
//
// Round theory: scan_step was ~85 µs/step (64 WGs, strided scalar weight
// loads -> L2-latency chain). Split each step into attn_step (batch-parallel,
// 64 WGs) + gates_step (column-parallel, 256 WGs, natural row-major weight
// streaming with float4, k-half split). fc GEMM: 2 cols/thread + B prefetch
// pipeline (was B-load latency bound at 38 TF).

static __device__ __forceinline__ float my_tanh(float x) {
    x = fminf(fmaxf(x, -15.f), 15.f);
    float e = __expf(2.f * x);
    return (e - 1.f) / (e + 1.f);
}
static __device__ __forceinline__ float my_sigmoid(float x) {
    return 1.f / (1.f + __expf(-x));
}

// ---------------------------------------------------------------------------
// Tiled fp32 transpose: out[c*R + r] = in[r*ld_in + c]   (out shape [C][R])
// ---------------------------------------------------------------------------
__global__ __launch_bounds__(256) void transpose_f32(
    const float* __restrict__ in, float* __restrict__ out,
    int R, int C, int ld_in)
{
    __shared__ float tile[32][33];
    int tc = blockIdx.x * 32;
    int tr = blockIdx.y * 32;
    int tx = threadIdx.x & 31, ty = threadIdx.x >> 5;  // 32 x 8
    #pragma unroll
    for (int i = 0; i < 4; i++) {
        int r = tr + ty + i * 8, c = tc + tx;
        tile[ty + i * 8][tx] = (r < R && c < C) ? in[(long)r * ld_in + c] : 0.f;
    }
    __syncthreads();
    #pragma unroll
    for (int i = 0; i < 4; i++) {
        int c = tc + ty + i * 8, r = tr + tx;
        if (c < C && r < R) out[(long)c * R + r] = tile[tx][ty + i * 8];
    }
}

// ---------------------------------------------------------------------------
// fp32 GEMM, 1 col/thread, 16 rows/block. Kept for att1 (N=256).
// ---------------------------------------------------------------------------
__global__ __launch_bounds__(256) void gemm_f32(
    const float* __restrict__ A, int lda,
    const float* __restrict__ B, int ldb,
    const float* __restrict__ bias,
    float* __restrict__ C, int ldc,
    int M, int N, int K)
{
    __shared__ float Asm[16 * 512];
    const int tid = threadIdx.x;
    const int n = blockIdx.x * 256 + tid;
    const bool active = n < N;
    const int nn = active ? n : (N - 1);
    const int m0 = blockIdx.y * 16;

    float acc[16];
    #pragma unroll
    for (int i = 0; i < 16; i++) acc[i] = 0.f;

    for (int kt = 0; kt < K; kt += 512) {
        for (int idx = tid; idx < 16 * 512; idx += 256) {
            int i = idx >> 9, kk = idx & 511;
            Asm[idx] = A[(long)(m0 + i) * lda + kt + kk];
        }
        __syncthreads();
        for (int k0 = 0; k0 < 512; k0 += 4) {
            float4 a4[16];
            #pragma unroll
            for (int i = 0; i < 16; i++)
                a4[i] = *(const float4*)(&Asm[i * 512 + k0]);
            #pragma unroll
            for (int j = 0; j < 4; j++) {
                float bv = B[(long)(kt + k0 + j) * ldb + nn];
                #pragma unroll
                for (int i = 0; i < 16; i++) {
                    float av = (j == 0) ? a4[i].x : (j == 1) ? a4[i].y
                             : (j == 2) ? a4[i].z : a4[i].w;
                    acc[i] = fmaf(av, bv, acc[i]);
                }
            }
        }
        __syncthreads();
    }

    if (active) {
        float bb = bias ? bias[n] : 0.f;
        #pragma unroll
        for (int i = 0; i < 16; i++)
            C[(long)(m0 + i) * ldc + n] = acc[i] + bb;
    }
}

// ---------------------------------------------------------------------------
// fp32 GEMM, 2 cols/thread (512 cols/block), 16 rows/block, B software
// pipeline. Block covers cols [bx*512, bx*512+512); 128 FMA per 8 B-loads.
// ---------------------------------------------------------------------------
__global__ __launch_bounds__(256) void gemm2_f32(
    const float* __restrict__ A, int lda,
    const float* __restrict__ B, int ldb,
    const float* __restrict__ bias,
    float* __restrict__ C, int ldc,
    int M, int N, int K)
{
    __shared__ float Asm[16 * 512];
    const int tid = threadIdx.x;
    const int n0 = blockIdx.x * 512 + tid;
    const int n1 = n0 + 256;
    const bool act0 = n0 < N, act1 = n1 < N;
    const int nn0 = act0 ? n0 : (N - 1);
    const int nn1 = act1 ? n1 : (N - 1);
    const int m0 = blockIdx.y * 16;

    float acc0[16], acc1[16];
    #pragma unroll
    for (int i = 0; i < 16; i++) { acc0[i] = 0.f; acc1[i] = 0.f; }

    for (int kt = 0; kt < K; kt += 512) {
        for (int idx = tid; idx < 16 * 512; idx += 256) {
            int i = idx >> 9, kk = idx & 511;
            Asm[idx] = A[(long)(m0 + i) * lda + kt + kk];
        }
        __syncthreads();

        float bv0[4], bv1[4];
        #pragma unroll
        for (int j = 0; j < 4; ++j) {
            bv0[j] = B[(size_t)(kt + j) * ldb + nn0];
            bv1[j] = B[(size_t)(kt + j) * ldb + nn1];
        }
        for (int k0 = 0; k0 < 512; k0 += 4) {
            float nb0[4], nb1[4];
            if (k0 + 4 < 512) {
                #pragma unroll
                for (int j = 0; j < 4; ++j) {
                    nb0[j] = B[(size_t)(kt + k0 + 4 + j) * ldb + nn0];
                    nb1[j] = B[(size_t)(kt + k0 + 4 + j) * ldb + nn1];
                }
            }
            #pragma unroll
            for (int half = 0; half < 2; ++half) {
                #pragma unroll
                for (int i = 0; i < 8; ++i) {
                    const int row = half * 8 + i;
                    const float4 a = *(const float4*)(&Asm[row * 512 + k0]);
                    acc0[row] = fmaf(a.x, bv0[0], acc0[row]);
                    acc0[row] = fmaf(a.y, bv0[1], acc0[row]);
                    acc0[row] = fmaf(a.z, bv0[2], acc0[row]);
                    acc0[row] = fmaf(a.w, bv0[3], acc0[row]);
                    acc1[row] = fmaf(a.x, bv1[0], acc1[row]);
                    acc1[row] = fmaf(a.y, bv1[1], acc1[row]);
                    acc1[row] = fmaf(a.z, bv1[2], acc1[row]);
                    acc1[row] = fmaf(a.w, bv1[3], acc1[row]);
                }
            }
            #pragma unroll
            for (int j = 0; j < 4; ++j) { bv0[j] = nb0[j]; bv1[j] = nb1[j]; }
        }
        __syncthreads();
    }

    if (act0) {
        const float bb = bias ? bias[n0] : 0.f;
        #pragma unroll
        for (int i = 0; i < 16; i++)
            C[(long)(m0 + i) * ldc + n0] = acc0[i] + bb;
    }
    if (act1) {
        const float bb = bias ? bias[n1] : 0.f;
        #pragma unroll
        for (int i = 0; i < 16; i++)
            C[(long)(m0 + i) * ldc + n1] = acc1[i] + bb;
    }
}

// ---------------------------------------------------------------------------
// Gather embedding rows: out[m,:] = emb[caps[m],:]  (m = b*50+t, 3200 rows)
// ---------------------------------------------------------------------------
__global__ __launch_bounds__(256) void gather_emb(
    const int* __restrict__ caps, const float* __restrict__ emb,
    float* __restrict__ out)
{
    const int m = blockIdx.x;
    const int cap = caps[m];
    const float* src = emb + (size_t)cap * 512;
    float* dst = out + (size_t)m * 512;
    dst[threadIdx.x] = src[threadIdx.x];
    dst[threadIdx.x + 256] = src[threadIdx.x + 256];
}

// ---------------------------------------------------------------------------
// attn_step: one WG per batch (64 WGs x 512 thr). att2 -> scores -> softmax
// -> context, all batch-local. W_daT[256][512] lets each thread stream its
// own row contiguously (float4). Writes ctx_g[64][512].
// ---------------------------------------------------------------------------
__global__ __launch_bounds__(512) void attn_step(
    const int t,
    const float* __restrict__ enc,    // [64,49,512]
    const float* __restrict__ att1,   // [64,49,256]
    const float* __restrict__ W_daT,  // [256][512]
    const float* __restrict__ b_da,   // [256]
    const float* __restrict__ W_fa,   // [256]
    const float* __restrict__ b_fa,   // [1]
    const float* __restrict__ h_g,    // [64][512]
    float* __restrict__ ctx_g)        // [64][512]
{
    __shared__ float sh_h[512];
    __shared__ float sh_att2[256];
    __shared__ float sh_part[512];
    __shared__ float sh_red[49 * 8];
    __shared__ float sh_s[64];

    const int tid = threadIdx.x;
    const int b = blockIdx.x;

    sh_h[tid] = (t == 0) ? 0.f : h_g[(size_t)b * 512 + tid];
    __syncthreads();

    // ---- att2 partials: j = tid>>1 (256 cols), kh = tid&1 (k-half)
    {
        const int j = tid >> 1, kh = tid & 1;
        const float4* w4 = (const float4*)(W_daT + (size_t)j * 512 + kh * 256);
        const float* hh = sh_h + kh * 256;
        float a = 0.f;
        #pragma unroll 8
        for (int kq = 0; kq < 64; ++kq) {
            const float4 w = w4[kq];
            const float4 x = *(const float4*)(hh + kq * 4);
            a = fmaf(x.x, w.x, a);
            a = fmaf(x.y, w.y, a);
            a = fmaf(x.z, w.z, a);
            a = fmaf(x.w, w.w, a);
        }
        sh_part[tid] = a;
    }
    __syncthreads();
    if (tid < 256) sh_att2[tid] = sh_part[tid * 2] + sh_part[tid * 2 + 1] + b_da[tid];
    __syncthreads();

    // ---- scores: 49 l x 8 chunks of 32 j = 392 tasks
    if (tid < 392) {
        const int l = tid >> 3, ch = tid & 7;
        const float4* a4 = (const float4*)(att1 + ((size_t)b * 49 + l) * 256 + ch * 32);
        const float* at2 = sh_att2 + ch * 32;
        const float* wf = W_fa + ch * 32;
        float s = 0.f;
        #pragma unroll
        for (int i = 0; i < 8; ++i) {
            const float4 v = a4[i];
            s += my_tanh(v.x + at2[i * 4 + 0]) * wf[i * 4 + 0];
            s += my_tanh(v.y + at2[i * 4 + 1]) * wf[i * 4 + 1];
            s += my_tanh(v.z + at2[i * 4 + 2]) * wf[i * 4 + 2];
            s += my_tanh(v.w + at2[i * 4 + 3]) * wf[i * 4 + 3];
        }
        sh_red[tid] = s;
    }
    __syncthreads();
    if (tid < 49) {
        const float* r = sh_red + tid * 8;
        sh_s[tid] = r[0] + r[1] + r[2] + r[3] + r[4] + r[5] + r[6] + r[7] + b_fa[0];
    }
    __syncthreads();

    // ---- softmax over L=49, wave 0 lane-parallel
    if (tid < 64) {
        const float v = (tid < 49) ? sh_s[tid] : -1e30f;
        float m = v;
        #pragma unroll
        for (int o = 32; o; o >>= 1) m = fmaxf(m, __shfl_xor(m, o));
        const float e = (tid < 49) ? __expf(v - m) : 0.f;
        float su = e;
        #pragma unroll
        for (int o = 32; o; o >>= 1) su += __shfl_xor(su, o);
        if (tid < 49) sh_s[tid] = e / su;
    }
    __syncthreads();

    // ---- context[d] = sum_l alpha[l] * enc[b,l,d]  (d = tid)
    {
        const float* e0 = enc + (size_t)b * 49 * 512 + tid;
        float c = 0.f;
        #pragma unroll
        for (int l = 0; l < 49; ++l) c = fmaf(sh_s[l], e0[(size_t)l * 512], c);
        ctx_g[(size_t)b * 512 + tid] = c;
    }
}

// ---------------------------------------------------------------------------
// gates_step: 256 WGs = 16 batch-quads x 16 j-slices (slice fastest in bid
// so bid%8 = slice%8 -> each XCD's L2 holds only 2 weight slices). 512 thr.
// Threads 0..383: (col 0..191, k-half 0..1); col<96 -> gh (W_hh natural row
// stream), col>=96 -> gi-ctx (W_ih natural row, offset 512). 4 batches per
// thread. Then combine halves + Gemb/b_hh, then GRU combine on 128 threads.
// ---------------------------------------------------------------------------
__global__ __launch_bounds__(512) void gates_step(
    const int t,
    const float* __restrict__ W_ih,   // [1536][1024] natural
    const float* __restrict__ W_hh,   // [1536][512]  natural
    const float* __restrict__ b_hh,   // [1536]
    const float* __restrict__ Gemb,   // [3200][1536] (includes b_ih)
    const float* __restrict__ ctx_g,  // [64][512]
    float* __restrict__ h_g,          // [64][512] in/out
    float* __restrict__ Hbuf)         // [3200][512]
{
    __shared__ float sh_h[4 * 512];
    __shared__ float sh_c[4 * 512];
    __shared__ float sh_part[384 * 4];   // [(kh*192+colL)*4 + bb]
    __shared__ float sh_gate[192 * 4];   // [colL*4 + bb]

    const int tid = threadIdx.x;
    const int g16 = blockIdx.x >> 4;     // batch quad 0..15
    const int sl  = blockIdx.x & 15;     // j-slice 0..15
    const int b0 = g16 * 4;

    for (int i = tid; i < 2048; i += 512) {
        sh_h[i] = (t == 0) ? 0.f : h_g[(size_t)b0 * 512 + i];
        sh_c[i] = ctx_g[(size_t)b0 * 512 + i];
    }
    __syncthreads();

    if (tid < 384) {
        const int colL = (tid < 192) ? tid : tid - 192;
        const int kh   = (tid < 192) ? 0 : 1;
        const bool is_gi = colL >= 96;
        const int cc = is_gi ? colL - 96 : colL;
        const int gate = cc >> 5, jj = cc & 31;
        const int n = gate * 512 + sl * 32 + jj;
        const float4* w4 = is_gi
            ? (const float4*)(W_ih + (size_t)n * 1024 + 512 + kh * 256)
            : (const float4*)(W_hh + (size_t)n * 512 + kh * 256);
        const float* xb = (is_gi ? sh_c : sh_h) + kh * 256;
        float a0 = 0.f, a1 = 0.f, a2 = 0.f, a3 = 0.f;
        #pragma unroll 8
        for (int kq = 0; kq < 64; ++kq) {
            const float4 w = w4[kq];
            const int k4 = kq * 4;
            const float4 x0 = *(const float4*)(xb + k4);
            const float4 x1 = *(const float4*)(xb + 512 + k4);
            const float4 x2 = *(const float4*)(xb + 1024 + k4);
            const float4 x3 = *(const float4*)(xb + 1536 + k4);
            a0 = fmaf(x0.x, w.x, a0); a0 = fmaf(x0.y, w.y, a0);
            a0 = fmaf(x0.z, w.z, a0); a0 = fmaf(x0.w, w.w, a0);
            a1 = fmaf(x1.x, w.x, a1); a1 = fmaf(x1.y, w.y, a1);
            a1 = fmaf(x1.z, w.z, a1); a1 = fmaf(x1.w, w.w, a1);
            a2 = fmaf(x2.x, w.x, a2); a2 = fmaf(x2.y, w.y, a2);
            a2 = fmaf(x2.z, w.z, a2); a2 = fmaf(x2.w, w.w, a2);
            a3 = fmaf(x3.x, w.x, a3); a3 = fmaf(x3.y, w.y, a3);
            a3 = fmaf(x3.z, w.z, a3); a3 = fmaf(x3.w, w.w, a3);
        }
        const int base = (kh * 192 + colL) * 4;
        sh_part[base + 0] = a0;
        sh_part[base + 1] = a1;
        sh_part[base + 2] = a2;
        sh_part[base + 3] = a3;
    }
    __syncthreads();

    // combine k-halves + bias/Gemb
    if (tid < 192) {
        const bool is_gi = tid >= 96;
        const int cc = is_gi ? tid - 96 : tid;
        const int gate = cc >> 5, jj = cc & 31;
        const int n = gate * 512 + sl * 32 + jj;
        #pragma unroll
        for (int bb = 0; bb < 4; ++bb) {
            float v = sh_part[tid * 4 + bb] + sh_part[(192 + tid) * 4 + bb];
            if (is_gi) v += Gemb[((size_t)(b0 + bb) * 50 + t) * 1536 + n];
            else       v += b_hh[n];
            sh_gate[tid * 4 + bb] = v;
        }
    }
    __syncthreads();

    // GRU combine: 128 threads = 4 batches x 32 j
    if (tid < 128) {
        const int bb = tid >> 5, jj = tid & 31;
        const int j = sl * 32 + jj;
        const float ghr = sh_gate[(jj) * 4 + bb];
        const float ghz = sh_gate[(32 + jj) * 4 + bb];
        const float ghn = sh_gate[(64 + jj) * 4 + bb];
        const float gir = sh_gate[(96 + jj) * 4 + bb];
        const float giz = sh_gate[(96 + 32 + jj) * 4 + bb];
        const float gin = sh_gate[(96 + 64 + jj) * 4 + bb];
        const float r  = my_sigmoid(gir + ghr);
        const float z  = my_sigmoid(giz + ghz);
        const float nn = my_tanh(gin + r * ghn);
        const float hold = sh_h[bb * 512 + j];
        const float hnew = (1.f - z) * nn + z * hold;
        h_g[(size_t)(b0 + bb) * 512 + j] = hnew;
        Hbuf[((size_t)(b0 + bb) * 50 + t) * 512 + j] = hnew;
    }
}

// ---------------------------------------------------------------------------
extern "C" void kernel_launch(void* const* d_in, const int* in_sizes, int n_in,
                              void* d_out, int out_size, void* d_ws, size_t ws_size,
                              hipStream_t stream) {
    const float* spatial = (const float*)d_in[0];
    const int*   captions= (const int*)d_in[1];
    const float* W_feat  = (const float*)d_in[2];
    const float* b_feat  = (const float*)d_in[3];
    const float* W_ea    = (const float*)d_in[4];
    const float* b_ea    = (const float*)d_in[5];
    const float* W_da    = (const float*)d_in[6];
    const float* b_da    = (const float*)d_in[7];
    const float* W_fa    = (const float*)d_in[8];
    const float* b_fa    = (const float*)d_in[9];
    const float* emb     = (const float*)d_in[10];
    const float* W_ih    = (const float*)d_in[11];
    const float* W_hh    = (const float*)d_in[12];
    const float* b_ih    = (const float*)d_in[13];
    const float* b_hh    = (const float*)d_in[14];
    const float* W_fc    = (const float*)d_in[15];
    const float* b_fc    = (const float*)d_in[16];
    float* out = (float*)d_out;

    // Workspace: ~43 MB fp32. Embt aliases Hbuf (consumed by the Gemb GEMM
    // before the scan writes Hbuf; same-stream ordering guarantees it).
    char* ws = (char*)d_ws;
    float* Wt_ih = (float*)ws; ws += (size_t)1024 * 1536 * 4;   //  6,291,456
    float* W_daT = (float*)ws; ws += (size_t)256 * 512 * 4;     //    524,288
    float* enc   = (float*)ws; ws += (size_t)3136 * 512 * 4;    //  6,422,528
    float* att1  = (float*)ws; ws += (size_t)3136 * 256 * 4;    //  3,211,264
    float* Hbuf  = (float*)ws; ws += (size_t)3200 * 512 * 4;    //  6,553,600
    float* Gemb  = (float*)ws; ws += (size_t)3200 * 1536 * 4;   // 19,660,800
    float* h_g   = (float*)ws; ws += (size_t)64 * 512 * 4;      //    131,072
    float* ctx_g = (float*)ws; ws += (size_t)64 * 512 * 4;      //    131,072
    float* Embt  = Hbuf;
    const size_t NEED = 6291456ull + 524288 + 6422528 + 3211264 + 6553600
                      + 19660800 + 131072 + 131072;
    if (ws_size < NEED) return;

    dim3 blk(256);
    // Wt_ih[1024][1536] = W_ih^T (for the Gemb GEMM, emb-part rows 0..511)
    transpose_f32<<<dim3(32, 48), blk, 0, stream>>>(W_ih, Wt_ih, 1536, 1024, 1024);
    // W_daT[256][512] = W_da^T (for attn_step row streaming)
    transpose_f32<<<dim3(8, 16), blk, 0, stream>>>(W_da, W_daT, 512, 256, 256);

    // Embt[m,:] = emb[captions[m],:]          [3200,512]  (m = b*50+t)
    gather_emb<<<dim3(3200), blk, 0, stream>>>(captions, emb, Embt);

    // enc = spatial @ W_feat + b_feat         [3136,512]
    gemm2_f32<<<dim3(1, 196), blk, 0, stream>>>(spatial, 2048, W_feat, 512, b_feat,
                                                enc, 512, 3136, 512, 2048);
    // att1 = enc @ W_ea + b_ea                [3136,256]
    gemm_f32<<<dim3(1, 196), blk, 0, stream>>>(enc, 512, W_ea, 256, b_ea,
                                               att1, 256, 3136, 256, 512);
    // Gemb = Embt @ Wt_ih[0:512,:] + b_ih     [3200,1536]  (h-independent gi)
    gemm2_f32<<<dim3(3, 200), blk, 0, stream>>>(Embt, 512, Wt_ih, 1536, b_ih,
                                                Gemb, 1536, 3200, 1536, 512);

    // recurrent scan: 2 launches per step (stream order = the only sync)
    for (int t = 0; t < 50; ++t) {
        attn_step<<<dim3(64), dim3(512), 0, stream>>>(t, enc, att1, W_daT,
                                                      b_da, W_fa, b_fa,
                                                      h_g, ctx_g);
        gates_step<<<dim3(256), dim3(512), 0, stream>>>(t, W_ih, W_hh, b_hh,
                                                        Gemb, ctx_g, h_g, Hbuf);
    }

    // logits = Hbuf @ W_fc + b_fc -> d_out    [3200,10000]
    gemm2_f32<<<dim3(20, 200), blk, 0, stream>>>(Hbuf, 512, W_fc, 10000, b_fc,
                                                 out, 10000, 3200, 10000, 512);
}